// Round 3
// baseline (1559.107 us; speedup 1.0000x reference)
//
#include <hip/hip_runtime.h>
#include <math.h>

constexpr int TVL = 7500;   // T*V
constexpr int CIN = 256;
constexpr int CO  = 256;
constexpr int KO  = 768;    // K * C_OUT
constexpr int KK3 = 2304;   // C_OUT * TK (reordered k' = dt*256 + c)
#define BNEPS 1e-5f

typedef __attribute__((ext_vector_type(8))) short short8;   // 8 bf16 = 4 VGPRs
typedef __attribute__((ext_vector_type(4))) float f32x4;
typedef unsigned short ushortT;

// RNE float->bf16 (raw u16), and back
static __device__ __forceinline__ ushortT f2bf(float v) {
    unsigned x = __float_as_uint(v);
    unsigned r = (x + 0x7fffu + ((x >> 16) & 1u)) >> 16;
    return (ushortT)r;
}
static __device__ __forceinline__ float bf2f(ushortT u) {
    return __uint_as_float((unsigned)u << 16);
}

// async global->LDS, 16B per lane. LDS dest must be wave-uniform base + lane*16.
static __device__ __forceinline__ void gll16(const void* g, void* l) {
    __builtin_amdgcn_global_load_lds(
        (const __attribute__((address_space(1))) void*)g,
        (__attribute__((address_space(3))) void*)l, 16, 0, 0);
}

// Bijective XCD-chunked blockIdx remap (m204 variant).
static __device__ __forceinline__ void xcd_remap(int gx, int gy,
                                                 int& bx, int& by, int& bz)
{
    const int gz = gridDim.z;
    const int total = gx * gy * gz;
    const int lin = blockIdx.x + gx * (blockIdx.y + gy * blockIdx.z);
    const int q = total >> 3, r = total & 7;
    const int xcd = lin & 7, idx = lin >> 3;
    const int nl = (xcd < r ? xcd * (q + 1) : r * (q + 1) + (xcd - r) * q) + idx;
    bx = nl % gx;
    const int rest = nl / gx;
    by = rest % gy;
    bz = rest / gy;
}

// ---------------------------------------------------------------------------
// Split weights: conv_w [768x256] -> hi/lo bf16, same layout. Also zero zb.
// ---------------------------------------------------------------------------
__global__ void ksplit_w1(const float* __restrict__ w,
                          ushortT* __restrict__ dH, ushortT* __restrict__ dL,
                          ushortT* __restrict__ zb)
{
    if (blockIdx.x == 0 && threadIdx.x < 16) zb[threadIdx.x] = 0;
    int i = blockIdx.x * 256 + threadIdx.x;
    if (i < KO * CIN) {
        float v = w[i];
        ushortT h = f2bf(v);
        dH[i] = h;
        dL[i] = f2bf(v - bf2f(h));
    }
}

// tconv_w [256][256][9] -> reordered [o][k'=dt*256+c] hi/lo bf16
__global__ void ksplit_w3(const float* __restrict__ w,
                          ushortT* __restrict__ dH, ushortT* __restrict__ dL)
{
    int i = blockIdx.x * 256 + threadIdx.x;
    if (i < CO * KK3) {
        int o = i / KK3, rem = i - o * KK3;
        int c = rem / 9, dt = rem - c * 9;
        float v = w[i];
        ushortT h = f2bf(v);
        int j = o * KK3 + dt * 256 + c;
        dH[j] = h;
        dL[j] = f2bf(v - bf2f(h));
    }
}

// ---------------------------------------------------------------------------
// Transpose+split: src [.][7500] f32 (per image z, row stride zstr) ->
// dst [7500][256] bf16 hi/lo
// ---------------------------------------------------------------------------
__global__ __launch_bounds__(256) void ktrans_split(
    const float* __restrict__ src, size_t zstr,
    ushortT* __restrict__ dH, ushortT* __restrict__ dL)
{
    __shared__ float tile[32][33];
    const int z = blockIdx.z;
    src += (size_t)z * zstr;
    dH  += (size_t)z * TVL * 256;
    dL  += (size_t)z * TVL * 256;
    const int tx = threadIdx.x & 31, ty = threadIdx.x >> 5;
    const int wBase = blockIdx.x * 32, cBase = blockIdx.y * 32;
    #pragma unroll
    for (int i = 0; i < 4; ++i) {
        int r = ty + i * 8;
        int w = wBase + tx;
        tile[r][tx] = (w < TVL) ? src[(size_t)(cBase + r) * TVL + w] : 0.f;
    }
    __syncthreads();
    #pragma unroll
    for (int i = 0; i < 4; ++i) {
        int wr = ty + i * 8;
        int w = wBase + wr;
        if (w < TVL) {
            float v = tile[tx][wr];
            ushortT hi = f2bf(v);
            ushortT lo = f2bf(v - bf2f(hi));
            dH[(size_t)w * 256 + cBase + tx] = hi;
            dL[(size_t)w * 256 + cBase + tx] = lo;
        }
    }
}

// ---------------------------------------------------------------------------
// Kernel 1 (MFMA): out1[ng][o][col] = sum_c W[o][c]*x[ng][c][col] + b[o]
// B: 2-phase double-buffered global_load_lds, XOR slot swizzle.
// A (weights): direct global->VGPR fragments (L2-resident, no LDS).
// ---------------------------------------------------------------------------
__global__ __launch_bounds__(256, 3) void k1_mfma(
    const ushortT* __restrict__ Wh, const ushortT* __restrict__ Wl,
    const ushortT* __restrict__ Xh, const ushortT* __restrict__ Xl,
    const ushortT* __restrict__ zb,
    const float* __restrict__ bias, float* __restrict__ out1)
{
    __shared__ __align__(16) short Bh[2][4096], Bl[2][4096];
    const int tid = threadIdx.x;
    int bx, by, bz;
    xcd_remap(gridDim.x, gridDim.y, bx, by, bz);
    const int ng = bz;
    const int rowBase = by * 128;
    const int colBase = bx * 128;
    const ushortT* XhN = Xh + (size_t)ng * TVL * 256;
    const ushortT* XlN = Xl + (size_t)ng * TVL * 256;

    f32x4 acc[4][4];
    #pragma unroll
    for (int a = 0; a < 4; ++a)
        #pragma unroll
        for (int b = 0; b < 4; ++b) acc[a][b] = (f32x4){0.f, 0.f, 0.f, 0.f};

    const int r0 = tid >> 2, s = tid & 3;          // staging row/slot
    const int wv = tid >> 6, lane = tid & 63;
    const int wy = wv >> 1, wx = wv & 1;
    const int q = lane >> 4, l15 = lane & 15;
    const int qs0 = s ^ ((r0 >> 1) & 3);           // source chunk
    const int qsr = q ^ ((l15 >> 1) & 3);          // read slot
    const int ldo0 = tid * 16, ldo1 = 4096 + tid * 16;
    const int bcol0 = colBase + r0, bcol1 = colBase + r0 + 64;

    // per-lane A fragment base (direct global reads)
    const ushortT* WhR = Wh + (size_t)(rowBase + wy * 64 + l15) * CIN + q * 8;
    const ushortT* WlR = Wl + (size_t)(rowBase + wy * 64 + l15) * CIN + q * 8;

    auto stageB = [&](int kk, int p) {
        short* bhp = Bh[p]; short* blp = Bl[p];
        const size_t goB0 = (size_t)bcol0 * 256 + kk + qs0 * 8;
        const size_t goB1 = (size_t)bcol1 * 256 + kk + qs0 * 8;
        gll16(bcol0 < TVL ? (const void*)(XhN + goB0) : (const void*)zb, (char*)bhp + ldo0);
        gll16(bcol0 < TVL ? (const void*)(XlN + goB0) : (const void*)zb, (char*)blp + ldo0);
        gll16(bcol1 < TVL ? (const void*)(XhN + goB1) : (const void*)zb, (char*)bhp + ldo1);
        gll16(bcol1 < TVL ? (const void*)(XlN + goB1) : (const void*)zb, (char*)blp + ldo1);
    };

    stageB(0, 0);
    __syncthreads();
    int p = 0;

    #pragma unroll 1
    for (int kk = 0; kk < CIN; kk += 32) {
        // A fragments straight from global (issued first -> deepest latency cover)
        short8 ah[4], al[4];
        #pragma unroll
        for (int mi = 0; mi < 4; ++mi) {
            ah[mi] = *(const short8*)(WhR + (size_t)mi * 16 * CIN + kk);
            al[mi] = *(const short8*)(WlR + (size_t)mi * 16 * CIN + kk);
        }
        if (kk + 32 < CIN) stageB(kk + 32, p ^ 1);

        const char* BhP = (const char*)Bh[p];
        const char* BlP = (const char*)Bl[p];
        short8 bh[4], bl[4];
        #pragma unroll
        for (int ni = 0; ni < 4; ++ni) {
            const int off = (wx * 64 + ni * 16 + l15) * 64 + qsr * 16;
            bh[ni] = *(const short8*)(BhP + off);
            bl[ni] = *(const short8*)(BlP + off);
        }
        #pragma unroll
        for (int mi = 0; mi < 4; ++mi)
            #pragma unroll
            for (int ni = 0; ni < 4; ++ni) {
                acc[mi][ni] = __builtin_amdgcn_mfma_f32_16x16x32_bf16(ah[mi], bh[ni], acc[mi][ni], 0, 0, 0);
                acc[mi][ni] = __builtin_amdgcn_mfma_f32_16x16x32_bf16(ah[mi], bl[ni], acc[mi][ni], 0, 0, 0);
                acc[mi][ni] = __builtin_amdgcn_mfma_f32_16x16x32_bf16(al[mi], bh[ni], acc[mi][ni], 0, 0, 0);
            }
        __syncthreads();
        p ^= 1;
    }

    float* out1n = out1 + (size_t)ng * KO * TVL;
    #pragma unroll
    for (int mi = 0; mi < 4; ++mi)
        #pragma unroll
        for (int rr = 0; rr < 4; ++rr) {
            const int row = rowBase + wy * 64 + mi * 16 + q * 4 + rr;
            const float bv = bias[row];
            #pragma unroll
            for (int ni = 0; ni < 4; ++ni) {
                const int col = colBase + wx * 64 + ni * 16 + l15;
                if (col < TVL)
                    out1n[(size_t)row * TVL + col] = acc[mi][ni][rr] + bv;
            }
        }
}

// ---------------------------------------------------------------------------
// Kernel 2: spatial graph contraction + BN1 + ReLU.
// h aliases out1's k=0 plane (stride KO rows); per-thread read-then-write safe.
// ---------------------------------------------------------------------------
__global__ __launch_bounds__(256) void k2_sgc(
    const float* out1, const float* __restrict__ A,
    const float* __restrict__ Mm, const float* __restrict__ g1,
    const float* __restrict__ b1, const float* __restrict__ m1,
    const float* __restrict__ v1, float* h)
{
    __shared__ __align__(16) float AMs[3 * 25 * 28];
    const int tid = threadIdx.x;
    for (int i = tid; i < 1875; i += 256)
        AMs[(i / 25) * 28 + (i % 25)] = A[i] * Mm[i];
    __syncthreads();

    const int r  = blockIdx.x * 256 + tid;
    const int t2 = r % 150;
    const int rc = r / 150;
    const int c  = rc & 255;
    const int ng = rc >> 8;
    const int t  = t2 * 2;

    const float* base = out1 + ((size_t)ng * KO + c) * TVL + t * 25;
    float o0[25], o1[25];
    #pragma unroll
    for (int w = 0; w < 25; ++w) { o0[w] = 0.f; o1[w] = 0.f; }

    for (int k = 0; k < 3; ++k) {
        const float* yp = base + (size_t)k * CO * TVL;
        float y0[25], y1[25];
        #pragma unroll
        for (int v = 0; v < 25; ++v) { y0[v] = yp[v]; y1[v] = yp[25 + v]; }
        const float* amk = &AMs[k * 25 * 28];
        for (int v = 0; v < 25; ++v) {
            const float* am = amk + v * 28;
            const float ya = y0[v], yb = y1[v];
            #pragma unroll
            for (int w = 0; w < 25; ++w) {
                const float a = am[w];
                o0[w] += ya * a;
                o1[w] += yb * a;
            }
        }
    }

    const float sc = g1[c] / sqrtf(v1[c] + BNEPS);
    const float bi = b1[c] - m1[c] * sc;
    float* hp = h + ((size_t)ng * KO + c) * TVL + t * 25;   // KO stride: k=0 plane
    #pragma unroll
    for (int w = 0; w < 25; ++w) {
        const float va = o0[w] * sc + bi;
        const float vb = o1[w] * sc + bi;
        hp[w]      = va > 0.f ? va : 0.f;
        hp[25 + w] = vb > 0.f ? vb : 0.f;
    }
}

// ---------------------------------------------------------------------------
// Kernel 3 (MFMA): temporal conv + BN2 + ReLU + residual.
// B: 2-phase double-buffered gll16 staging; A: direct global->VGPR.
// ---------------------------------------------------------------------------
__global__ __launch_bounds__(256, 3) void k3_mfma(
    const ushortT* __restrict__ Wh, const ushortT* __restrict__ Wl,
    const ushortT* __restrict__ Hh, const ushortT* __restrict__ Hl,
    const ushortT* __restrict__ zb,
    const float* __restrict__ tb, const float* __restrict__ g2,
    const float* __restrict__ b2, const float* __restrict__ m2,
    const float* __restrict__ v2, const float* __restrict__ x,
    float* __restrict__ out, int n0)
{
    __shared__ __align__(16) short Bh[2][4096], Bl[2][4096];
    const int tid = threadIdx.x;
    int bx, by, bz;
    xcd_remap(gridDim.x, gridDim.y, bx, by, bz);
    const int ng = bz;
    const int rowBase = by * 128;
    const int colBase = bx * 128;
    const ushortT* HhN = Hh + (size_t)ng * TVL * 256;
    const ushortT* HlN = Hl + (size_t)ng * TVL * 256;

    f32x4 acc[4][4];
    #pragma unroll
    for (int a = 0; a < 4; ++a)
        #pragma unroll
        for (int b = 0; b < 4; ++b) acc[a][b] = (f32x4){0.f, 0.f, 0.f, 0.f};

    const int r0 = tid >> 2, s = tid & 3;
    const int wv = tid >> 6, lane = tid & 63;
    const int wy = wv >> 1, wx = wv & 1;
    const int q = lane >> 4, l15 = lane & 15;
    const int qs0 = s ^ ((r0 >> 1) & 3);
    const int qsr = q ^ ((l15 >> 1) & 3);
    const int ldo0 = tid * 16, ldo1 = 4096 + tid * 16;
    const int bcol0 = colBase + r0, bcol1 = colBase + r0 + 64;

    const ushortT* WhR = Wh + (size_t)(rowBase + wy * 64 + l15) * KK3 + q * 8;
    const ushortT* WlR = Wl + (size_t)(rowBase + wy * 64 + l15) * KK3 + q * 8;

    auto stageB = [&](int kk, int p) {
        short* bhp = Bh[p]; short* blp = Bl[p];
        const int dt = kk >> 8;
        const int c0 = kk & 255;
        const int shift = dt * 25 - 100;           // (dt-4)*25
        const int gcol0 = bcol0 + shift, gcol1 = bcol1 + shift;
        const bool ok0 = (bcol0 < TVL) && ((unsigned)gcol0 < (unsigned)TVL);
        const bool ok1 = (bcol1 < TVL) && ((unsigned)gcol1 < (unsigned)TVL);
        const size_t goB0 = (size_t)gcol0 * 256 + c0 + qs0 * 8;
        const size_t goB1 = (size_t)gcol1 * 256 + c0 + qs0 * 8;
        gll16(ok0 ? (const void*)(HhN + goB0) : (const void*)zb, (char*)bhp + ldo0);
        gll16(ok0 ? (const void*)(HlN + goB0) : (const void*)zb, (char*)blp + ldo0);
        gll16(ok1 ? (const void*)(HhN + goB1) : (const void*)zb, (char*)bhp + ldo1);
        gll16(ok1 ? (const void*)(HlN + goB1) : (const void*)zb, (char*)blp + ldo1);
    };

    stageB(0, 0);
    __syncthreads();
    int p = 0;

    #pragma unroll 1
    for (int kk = 0; kk < KK3; kk += 32) {
        short8 ah[4], al[4];
        #pragma unroll
        for (int mi = 0; mi < 4; ++mi) {
            ah[mi] = *(const short8*)(WhR + (size_t)mi * 16 * KK3 + kk);
            al[mi] = *(const short8*)(WlR + (size_t)mi * 16 * KK3 + kk);
        }
        if (kk + 32 < KK3) stageB(kk + 32, p ^ 1);

        const char* BhP = (const char*)Bh[p];
        const char* BlP = (const char*)Bl[p];
        short8 bh[4], bl[4];
        #pragma unroll
        for (int ni = 0; ni < 4; ++ni) {
            const int off = (wx * 64 + ni * 16 + l15) * 64 + qsr * 16;
            bh[ni] = *(const short8*)(BhP + off);
            bl[ni] = *(const short8*)(BlP + off);
        }
        #pragma unroll
        for (int mi = 0; mi < 4; ++mi)
            #pragma unroll
            for (int ni = 0; ni < 4; ++ni) {
                acc[mi][ni] = __builtin_amdgcn_mfma_f32_16x16x32_bf16(ah[mi], bh[ni], acc[mi][ni], 0, 0, 0);
                acc[mi][ni] = __builtin_amdgcn_mfma_f32_16x16x32_bf16(ah[mi], bl[ni], acc[mi][ni], 0, 0, 0);
                acc[mi][ni] = __builtin_amdgcn_mfma_f32_16x16x32_bf16(al[mi], bh[ni], acc[mi][ni], 0, 0, 0);
            }
        __syncthreads();
        p ^= 1;
    }

    const float* xn = x   + (size_t)(n0 + ng) * CO * TVL;
    float*       on = out + (size_t)(n0 + ng) * CO * TVL;
    #pragma unroll
    for (int mi = 0; mi < 4; ++mi)
        #pragma unroll
        for (int rr = 0; rr < 4; ++rr) {
            const int row = rowBase + wy * 64 + mi * 16 + q * 4 + rr;
            const float sc = g2[row] / sqrtf(v2[row] + BNEPS);
            const float bb = (tb[row] - m2[row]) * sc + b2[row];
            #pragma unroll
            for (int ni = 0; ni < 4; ++ni) {
                const int col = colBase + wx * 64 + ni * 16 + l15;
                if (col < TVL) {
                    const size_t o = (size_t)row * TVL + col;
                    on[o] = fmaxf(acc[mi][ni][rr] * sc + bb, 0.f) + xn[o];
                }
            }
        }
}

// ---------------------------------------------------------------------------
extern "C" void kernel_launch(void* const* d_in, const int* in_sizes, int n_in,
                              void* d_out, int out_size, void* d_ws, size_t ws_size,
                              hipStream_t stream)
{
    const float* x  = (const float*)d_in[0];
    const float* A  = (const float*)d_in[1];
    const float* Mm = (const float*)d_in[3];
    const float* cw = (const float*)d_in[4];
    const float* cb = (const float*)d_in[5];
    const float* g1 = (const float*)d_in[6];
    const float* b1 = (const float*)d_in[7];
    const float* m1 = (const float*)d_in[8];
    const float* v1 = (const float*)d_in[9];
    const float* tw = (const float*)d_in[10];
    const float* tb = (const float*)d_in[11];
    const float* g2 = (const float*)d_in[12];
    const float* b2 = (const float*)d_in[13];
    const float* m2 = (const float*)d_in[14];
    const float* v2 = (const float*)d_in[15];
    float* out = (float*)d_out;

    // Workspace layout: zero pad buffer (256 B), split weights, then per-group.
    ushortT* zb  = (ushortT*)d_ws;
    ushortT* W1h = (ushortT*)((char*)d_ws + 256);
    ushortT* W1l = W1h + KO * CIN;
    ushortT* W3h = W1l + KO * CIN;                 // 256*2304
    ushortT* W3l = W3h + CO * KK3;
    char* dyn = (char*)(W3l + CO * KK3);
    const size_t fixed = (size_t)(dyn - (char*)d_ws);
    const size_t avail = ws_size > fixed ? ws_size - fixed : 0;
    // per-n: out1 f32 (hbuf aliases its k=0 plane) + shared X/H-transposed hi/lo
    const size_t perN = (size_t)KO * TVL * 4 + 2 * (size_t)TVL * 256 * 2;
    int g = 16;
    while (g > 1 && (size_t)g * perN > avail) g >>= 1;

    float*   out1 = (float*)dyn;
    ushortT* Xh   = (ushortT*)(out1 + (size_t)g * KO * TVL);
    ushortT* Xl   = Xh + (size_t)g * TVL * 256;

    hipLaunchKernelGGL(ksplit_w1, dim3((KO * CIN + 255) / 256), dim3(256), 0, stream, cw, W1h, W1l, zb);
    hipLaunchKernelGGL(ksplit_w3, dim3((CO * KK3 + 255) / 256), dim3(256), 0, stream, tw, W3h, W3l);

    for (int n0 = 0; n0 < 16; n0 += g) {
        hipLaunchKernelGGL(ktrans_split, dim3(235, 8, g), dim3(256), 0, stream,
                           x + (size_t)n0 * CIN * TVL, (size_t)CIN * TVL, Xh, Xl);
        hipLaunchKernelGGL(k1_mfma, dim3(59, 6, g), dim3(256), 0, stream,
                           W1h, W1l, Xh, Xl, zb, cb, out1);
        hipLaunchKernelGGL(k2_sgc, dim3(g * 150), dim3(256), 0, stream,
                           out1, A, Mm, g1, b1, m1, v1, out1 /* h = k=0 plane */);
        hipLaunchKernelGGL(ktrans_split, dim3(235, 8, g), dim3(256), 0, stream,
                           out1, (size_t)KO * TVL, Xh, Xl);
        hipLaunchKernelGGL(k3_mfma, dim3(59, 2, g), dim3(256), 0, stream,
                           W3h, W3l, Xh, Xl, zb, tb, g2, b2, m2, v2, x, out, n0);
    }
}

// Round 5
// 1205.589 us; speedup vs baseline: 1.2932x; 1.2932x over previous
//
#include <hip/hip_runtime.h>
#include <math.h>

constexpr int TVL = 7500;   // T*V
constexpr int CIN = 256;
constexpr int CO  = 256;
constexpr int KO  = 768;    // K * C_OUT
constexpr int KK3 = 2304;   // C_OUT * TK (reordered k' = dt*256 + c)
#define BNEPS 1e-5f

typedef __attribute__((ext_vector_type(8))) short short8;   // 8 bf16 = 4 VGPRs
typedef __attribute__((ext_vector_type(4))) float f32x4;
typedef unsigned short ushortT;

// RNE float->bf16 (raw u16), and back
static __device__ __forceinline__ ushortT f2bf(float v) {
    unsigned x = __float_as_uint(v);
    unsigned r = (x + 0x7fffu + ((x >> 16) & 1u)) >> 16;
    return (ushortT)r;
}
static __device__ __forceinline__ float bf2f(ushortT u) {
    return __uint_as_float((unsigned)u << 16);
}

// async global->LDS, 16B per lane. LDS dest must be wave-uniform base + lane*16.
static __device__ __forceinline__ void gll16(const void* g, void* l) {
    __builtin_amdgcn_global_load_lds(
        (const __attribute__((address_space(1))) void*)g,
        (__attribute__((address_space(3))) void*)l, 16, 0, 0);
}

// Bijective XCD-chunked blockIdx remap (m204 variant).
static __device__ __forceinline__ void xcd_remap(int gx, int gy,
                                                 int& bx, int& by, int& bz)
{
    const int gz = gridDim.z;
    const int total = gx * gy * gz;
    const int lin = blockIdx.x + gx * (blockIdx.y + gy * blockIdx.z);
    const int q = total >> 3, r = total & 7;
    const int xcd = lin & 7, idx = lin >> 3;
    const int nl = (xcd < r ? xcd * (q + 1) : r * (q + 1) + (xcd - r) * q) + idx;
    bx = nl % gx;
    const int rest = nl / gx;
    by = rest % gy;
    bz = rest / gy;
}

// ---------------------------------------------------------------------------
// Split weights: conv_w [768x256] -> hi/lo bf16, same layout. Also zero zb.
// ---------------------------------------------------------------------------
__global__ void ksplit_w1(const float* __restrict__ w,
                          ushortT* __restrict__ dH, ushortT* __restrict__ dL,
                          ushortT* __restrict__ zb)
{
    if (blockIdx.x == 0 && threadIdx.x < 128) zb[threadIdx.x] = 0;
    int i = blockIdx.x * 256 + threadIdx.x;
    if (i < KO * CIN) {
        float v = w[i];
        ushortT h = f2bf(v);
        dH[i] = h;
        dL[i] = f2bf(v - bf2f(h));
    }
}

// tconv_w [256][256][9] -> reordered [o][k'=dt*256+c] hi/lo bf16
__global__ void ksplit_w3(const float* __restrict__ w,
                          ushortT* __restrict__ dH, ushortT* __restrict__ dL)
{
    int i = blockIdx.x * 256 + threadIdx.x;
    if (i < CO * KK3) {
        int o = i / KK3, rem = i - o * KK3;
        int c = rem / 9, dt = rem - c * 9;
        float v = w[i];
        ushortT h = f2bf(v);
        int j = o * KK3 + dt * 256 + c;
        dH[j] = h;
        dL[j] = f2bf(v - bf2f(h));
    }
}

// ---------------------------------------------------------------------------
// Transpose+split: src [.][7500] f32 (per image z, row stride zstr) ->
// dst [7500][256] bf16 hi/lo
// ---------------------------------------------------------------------------
__global__ __launch_bounds__(256) void ktrans_split(
    const float* __restrict__ src, size_t zstr,
    ushortT* __restrict__ dH, ushortT* __restrict__ dL)
{
    __shared__ float tile[32][33];
    const int z = blockIdx.z;
    src += (size_t)z * zstr;
    dH  += (size_t)z * TVL * 256;
    dL  += (size_t)z * TVL * 256;
    const int tx = threadIdx.x & 31, ty = threadIdx.x >> 5;
    const int wBase = blockIdx.x * 32, cBase = blockIdx.y * 32;
    #pragma unroll
    for (int i = 0; i < 4; ++i) {
        int r = ty + i * 8;
        int w = wBase + tx;
        tile[r][tx] = (w < TVL) ? src[(size_t)(cBase + r) * TVL + w] : 0.f;
    }
    __syncthreads();
    #pragma unroll
    for (int i = 0; i < 4; ++i) {
        int wr = ty + i * 8;
        int w = wBase + wr;
        if (w < TVL) {
            float v = tile[tx][wr];
            ushortT hi = f2bf(v);
            ushortT lo = f2bf(v - bf2f(hi));
            dH[(size_t)w * 256 + cBase + tx] = hi;
            dL[(size_t)w * 256 + cBase + tx] = lo;
        }
    }
}

// ---------------------------------------------------------------------------
// Kernel 1 (MFMA): out1[ng][o][col] = sum_c W[o][c]*x[ng][c][col] + b[o]
// 2-phase double-buffered global_load_lds staging, XOR slot swizzle. (R2 form)
// ---------------------------------------------------------------------------
__global__ __launch_bounds__(256) void k1_mfma(
    const ushortT* __restrict__ Wh, const ushortT* __restrict__ Wl,
    const ushortT* __restrict__ Xh, const ushortT* __restrict__ Xl,
    const ushortT* __restrict__ zb,
    const float* __restrict__ bias, float* __restrict__ out1)
{
    __shared__ __align__(16) short Ah[2][4096], Al[2][4096], Bh[2][4096], Bl[2][4096];
    const int tid = threadIdx.x;
    int bx, by, bz;
    xcd_remap(gridDim.x, gridDim.y, bx, by, bz);
    const int ng = bz;
    const int rowBase = by * 128;
    const int colBase = bx * 128;
    const ushortT* XhN = Xh + (size_t)ng * TVL * 256;
    const ushortT* XlN = Xl + (size_t)ng * TVL * 256;

    f32x4 acc[4][4];
    #pragma unroll
    for (int a = 0; a < 4; ++a)
        #pragma unroll
        for (int b = 0; b < 4; ++b) acc[a][b] = (f32x4){0.f, 0.f, 0.f, 0.f};

    const int r0 = tid >> 2, s = tid & 3;          // staging row/slot
    const int wv = tid >> 6, lane = tid & 63;
    const int wy = wv >> 1, wx = wv & 1;
    const int q = lane >> 4, l15 = lane & 15;
    const int qs0 = s ^ ((r0 >> 1) & 3);           // source chunk
    const int qsr = q ^ ((l15 >> 1) & 3);          // read slot
    const int ldo0 = tid * 16, ldo1 = 4096 + tid * 16;
    const int bcol0 = colBase + r0, bcol1 = colBase + r0 + 64;

    auto stage = [&](int kk, int p) {
        short* ahp = Ah[p]; short* alp = Al[p];
        short* bhp = Bh[p]; short* blp = Bl[p];
        const size_t goA = (size_t)(rowBase + r0) * CIN + kk + qs0 * 8;
        gll16(Wh + goA, (char*)ahp + ldo0);
        gll16(Wl + goA, (char*)alp + ldo0);
        gll16(Wh + goA + (size_t)64 * CIN, (char*)ahp + ldo1);
        gll16(Wl + goA + (size_t)64 * CIN, (char*)alp + ldo1);
        const size_t goB0 = (size_t)bcol0 * 256 + kk + qs0 * 8;
        const size_t goB1 = (size_t)bcol1 * 256 + kk + qs0 * 8;
        gll16(bcol0 < TVL ? (const void*)(XhN + goB0) : (const void*)zb, (char*)bhp + ldo0);
        gll16(bcol0 < TVL ? (const void*)(XlN + goB0) : (const void*)zb, (char*)blp + ldo0);
        gll16(bcol1 < TVL ? (const void*)(XhN + goB1) : (const void*)zb, (char*)bhp + ldo1);
        gll16(bcol1 < TVL ? (const void*)(XlN + goB1) : (const void*)zb, (char*)blp + ldo1);
    };

    stage(0, 0);
    __syncthreads();
    int p = 0;

    #pragma unroll 1
    for (int kk = 0; kk < CIN; kk += 32) {
        if (kk + 32 < CIN) stage(kk + 32, p ^ 1);

        const char* AhP = (const char*)Ah[p];
        const char* AlP = (const char*)Al[p];
        const char* BhP = (const char*)Bh[p];
        const char* BlP = (const char*)Bl[p];
        short8 ah[4], al[4], bh[4], bl[4];
        #pragma unroll
        for (int mi = 0; mi < 4; ++mi) {
            const int off = (wy * 64 + mi * 16 + l15) * 64 + qsr * 16;
            ah[mi] = *(const short8*)(AhP + off);
            al[mi] = *(const short8*)(AlP + off);
        }
        #pragma unroll
        for (int ni = 0; ni < 4; ++ni) {
            const int off = (wx * 64 + ni * 16 + l15) * 64 + qsr * 16;
            bh[ni] = *(const short8*)(BhP + off);
            bl[ni] = *(const short8*)(BlP + off);
        }
        #pragma unroll
        for (int mi = 0; mi < 4; ++mi)
            #pragma unroll
            for (int ni = 0; ni < 4; ++ni) {
                acc[mi][ni] = __builtin_amdgcn_mfma_f32_16x16x32_bf16(ah[mi], bh[ni], acc[mi][ni], 0, 0, 0);
                acc[mi][ni] = __builtin_amdgcn_mfma_f32_16x16x32_bf16(ah[mi], bl[ni], acc[mi][ni], 0, 0, 0);
                acc[mi][ni] = __builtin_amdgcn_mfma_f32_16x16x32_bf16(al[mi], bh[ni], acc[mi][ni], 0, 0, 0);
            }
        __syncthreads();
        p ^= 1;
    }

    float* out1n = out1 + (size_t)ng * KO * TVL;
    #pragma unroll
    for (int mi = 0; mi < 4; ++mi)
        #pragma unroll
        for (int rr = 0; rr < 4; ++rr) {
            const int row = rowBase + wy * 64 + mi * 16 + q * 4 + rr;
            const float bv = bias[row];
            #pragma unroll
            for (int ni = 0; ni < 4; ++ni) {
                const int col = colBase + wx * 64 + ni * 16 + l15;
                if (col < TVL)
                    out1n[(size_t)row * TVL + col] = acc[mi][ni][rr] + bv;
            }
        }
}

// ---------------------------------------------------------------------------
// Kernel 2: spatial graph contraction + BN1 + ReLU.
// h aliases out1's k=0 plane (stride KO rows); per-thread read-then-write safe.
// ---------------------------------------------------------------------------
__global__ __launch_bounds__(256) void k2_sgc(
    const float* out1, const float* __restrict__ A,
    const float* __restrict__ Mm, const float* __restrict__ g1,
    const float* __restrict__ b1, const float* __restrict__ m1,
    const float* __restrict__ v1, float* h)
{
    __shared__ __align__(16) float AMs[3 * 25 * 28];
    const int tid = threadIdx.x;
    for (int i = tid; i < 1875; i += 256)
        AMs[(i / 25) * 28 + (i % 25)] = A[i] * Mm[i];
    __syncthreads();

    const int r  = blockIdx.x * 256 + tid;
    const int t2 = r % 150;
    const int rc = r / 150;
    const int c  = rc & 255;
    const int ng = rc >> 8;
    const int t  = t2 * 2;

    const float* base = out1 + ((size_t)ng * KO + c) * TVL + t * 25;
    float o0[25], o1[25];
    #pragma unroll
    for (int w = 0; w < 25; ++w) { o0[w] = 0.f; o1[w] = 0.f; }

    for (int k = 0; k < 3; ++k) {
        const float* yp = base + (size_t)k * CO * TVL;
        float y0[25], y1[25];
        #pragma unroll
        for (int v = 0; v < 25; ++v) { y0[v] = yp[v]; y1[v] = yp[25 + v]; }
        const float* amk = &AMs[k * 25 * 28];
        for (int v = 0; v < 25; ++v) {
            const float* am = amk + v * 28;
            const float ya = y0[v], yb = y1[v];
            #pragma unroll
            for (int w = 0; w < 25; ++w) {
                const float a = am[w];
                o0[w] += ya * a;
                o1[w] += yb * a;
            }
        }
    }

    const float sc = g1[c] / sqrtf(v1[c] + BNEPS);
    const float bi = b1[c] - m1[c] * sc;
    float* hp = h + ((size_t)ng * KO + c) * TVL + t * 25;   // KO stride: k=0 plane
    #pragma unroll
    for (int w = 0; w < 25; ++w) {
        const float va = o0[w] * sc + bi;
        const float vb = o1[w] * sc + bi;
        hp[w]      = va > 0.f ? va : 0.f;
        hp[25 + w] = vb > 0.f ? vb : 0.f;
    }
}

// ---------------------------------------------------------------------------
// Kernel 3 (MFMA): temporal conv + BN2 + ReLU + residual.
// Strip-reuse version: per 32-channel chunk, stage a 384-col H strip ONCE
// (12 gll16 from HBM), then 9 dt-passes read shifted 128-col windows of it.
// A (weights) double-buffered in LDS, staged one step ahead (L2-hot drain).
// LDS: strip 48KB + A dbuf 32KB = 80KB -> 2 blocks/CU.
// ---------------------------------------------------------------------------
__global__ __launch_bounds__(256) void k3_mfma(
    const ushortT* __restrict__ Wh, const ushortT* __restrict__ Wl,
    const ushortT* __restrict__ Hh, const ushortT* __restrict__ Hl,
    const ushortT* __restrict__ zb,
    const float* __restrict__ tb, const float* __restrict__ g2,
    const float* __restrict__ b2, const float* __restrict__ m2,
    const float* __restrict__ v2, const float* __restrict__ x,
    float* __restrict__ out, int n0)
{
    __shared__ __align__(16) short Sh[384 * 32], Sl[384 * 32];   // 24KB each
    __shared__ __align__(16) short Ah[2][4096], Al[2][4096];     // 8KB each
    const int tid = threadIdx.x;
    int bx, by, bz;
    xcd_remap(gridDim.x, gridDim.y, bx, by, bz);
    const int ng = bz;
    const int rowBase = by * 128;
    const int colBase = bx * 128;
    const ushortT* HhN = Hh + (size_t)ng * TVL * 256;
    const ushortT* HlN = Hl + (size_t)ng * TVL * 256;

    f32x4 acc[4][4];
    #pragma unroll
    for (int a = 0; a < 4; ++a)
        #pragma unroll
        for (int b = 0; b < 4; ++b) acc[a][b] = (f32x4){0.f, 0.f, 0.f, 0.f};

    const int r0 = tid >> 2, s = tid & 3;          // staging row(col)/slot
    const int wv = tid >> 6, lane = tid & 63;
    const int wy = wv >> 1, wx = wv & 1;
    const int q = lane >> 4, l15 = lane & 15;
    const int qs0 = s ^ ((r0 >> 1) & 3);           // source chunk (swizzle key)
    const int qsr = q ^ ((l15 >> 1) & 3);          // A read slot
    const int ldo0 = tid * 16, ldo1 = 4096 + tid * 16;

    // Strip: local col sc holds global col (colBase-128+sc), channels c0..c0+31.
    // Layout: byte = sc*64 + slot*16, slot pre-swizzled on source side.
    auto stageStrip = [&](int c0) {
        #pragma unroll
        for (int i = 0; i < 6; ++i) {
            const int gcol = colBase - 128 + i * 64 + r0;
            const bool ok = (unsigned)gcol < (unsigned)TVL;
            const size_t go = (size_t)gcol * 256 + c0 + qs0 * 8;
            gll16(ok ? (const void*)(HhN + go) : (const void*)zb,
                  (char*)Sh + i * 4096 + tid * 16);
            gll16(ok ? (const void*)(HlN + go) : (const void*)zb,
                  (char*)Sl + i * 4096 + tid * 16);
        }
    };
    auto stageA = [&](int kp, int p) {
        short* ahp = Ah[p]; short* alp = Al[p];
        const size_t goA = (size_t)(rowBase + r0) * KK3 + kp + qs0 * 8;
        gll16(Wh + goA, (char*)ahp + ldo0);
        gll16(Wl + goA, (char*)alp + ldo0);
        gll16(Wh + goA + (size_t)64 * KK3, (char*)ahp + ldo1);
        gll16(Wl + goA + (size_t)64 * KK3, (char*)alp + ldo1);
    };

    stageA(0, 0);
    int p = 0;

    #pragma unroll 1
    for (int cc = 0; cc < 8; ++cc) {
        const int c0 = cc * 32;
        stageStrip(c0);          // once per chunk: the only HBM-deep drain
        __syncthreads();

        #pragma unroll 1
        for (int dt = 0; dt < 9; ++dt) {
            // stage next A (one step ahead, L2-hot)
            {
                int ndt = dt + 1, nc0 = c0;
                if (ndt == 9) { ndt = 0; nc0 += 32; }
                if (nc0 < 256) stageA(ndt * 256 + nc0, p ^ 1);
            }

            const char* AhP = (const char*)Ah[p];
            const char* AlP = (const char*)Al[p];
            short8 ah[4], al[4], bh[4], bl[4];
            #pragma unroll
            for (int mi = 0; mi < 4; ++mi) {
                const int off = (wy * 64 + mi * 16 + l15) * 64 + qsr * 16;
                ah[mi] = *(const short8*)(AhP + off);
                al[mi] = *(const short8*)(AlP + off);
            }
            // B window: global col = colBase + wx*64+ni*16+l15 + (dt-4)*25
            //   -> strip col sc = wx*64 + ni*16 + l15 + dt*25 + 28  (28..355)
            const int sbase = wx * 64 + dt * 25 + 28;
            #pragma unroll
            for (int ni = 0; ni < 4; ++ni) {
                const int sc = sbase + ni * 16 + l15;
                const int off = sc * 64 + ((q ^ ((sc >> 1) & 3)) << 4);
                bh[ni] = *(const short8*)((const char*)Sh + off);
                bl[ni] = *(const short8*)((const char*)Sl + off);
            }
            #pragma unroll
            for (int mi = 0; mi < 4; ++mi)
                #pragma unroll
                for (int ni = 0; ni < 4; ++ni) {
                    acc[mi][ni] = __builtin_amdgcn_mfma_f32_16x16x32_bf16(ah[mi], bh[ni], acc[mi][ni], 0, 0, 0);
                    acc[mi][ni] = __builtin_amdgcn_mfma_f32_16x16x32_bf16(ah[mi], bl[ni], acc[mi][ni], 0, 0, 0);
                    acc[mi][ni] = __builtin_amdgcn_mfma_f32_16x16x32_bf16(al[mi], bh[ni], acc[mi][ni], 0, 0, 0);
                }
            __syncthreads();
            p ^= 1;
        }
    }

    const float* xn = x   + (size_t)(n0 + ng) * CO * TVL;
    float*       on = out + (size_t)(n0 + ng) * CO * TVL;
    #pragma unroll
    for (int mi = 0; mi < 4; ++mi)
        #pragma unroll
        for (int rr = 0; rr < 4; ++rr) {
            const int row = rowBase + wy * 64 + mi * 16 + q * 4 + rr;
            const float sc = g2[row] / sqrtf(v2[row] + BNEPS);
            const float bb = (tb[row] - m2[row]) * sc + b2[row];
            #pragma unroll
            for (int ni = 0; ni < 4; ++ni) {
                const int col = colBase + wx * 64 + ni * 16 + l15;
                if (col < TVL) {
                    const size_t o = (size_t)row * TVL + col;
                    on[o] = fmaxf(acc[mi][ni][rr] * sc + bb, 0.f) + xn[o];
                }
            }
        }
}

// ---------------------------------------------------------------------------
extern "C" void kernel_launch(void* const* d_in, const int* in_sizes, int n_in,
                              void* d_out, int out_size, void* d_ws, size_t ws_size,
                              hipStream_t stream)
{
    const float* x  = (const float*)d_in[0];
    const float* A  = (const float*)d_in[1];
    const float* Mm = (const float*)d_in[3];
    const float* cw = (const float*)d_in[4];
    const float* cb = (const float*)d_in[5];
    const float* g1 = (const float*)d_in[6];
    const float* b1 = (const float*)d_in[7];
    const float* m1 = (const float*)d_in[8];
    const float* v1 = (const float*)d_in[9];
    const float* tw = (const float*)d_in[10];
    const float* tb = (const float*)d_in[11];
    const float* g2 = (const float*)d_in[12];
    const float* b2 = (const float*)d_in[13];
    const float* m2 = (const float*)d_in[14];
    const float* v2 = (const float*)d_in[15];
    float* out = (float*)d_out;

    // Workspace layout: zero pad buffer (256 B), split weights, then per-group.
    ushortT* zb  = (ushortT*)d_ws;
    ushortT* W1h = (ushortT*)((char*)d_ws + 256);
    ushortT* W1l = W1h + KO * CIN;
    ushortT* W3h = W1l + KO * CIN;                 // 256*2304
    ushortT* W3l = W3h + CO * KK3;
    char* dyn = (char*)(W3l + CO * KK3);
    const size_t fixed = (size_t)(dyn - (char*)d_ws);
    const size_t avail = ws_size > fixed ? ws_size - fixed : 0;
    // per-n: out1 f32 (hbuf aliases its k=0 plane) + shared X/H-transposed hi/lo
    const size_t perN = (size_t)KO * TVL * 4 + 2 * (size_t)TVL * 256 * 2;
    int g = 16;
    while (g > 1 && (size_t)g * perN > avail) g >>= 1;

    float*   out1 = (float*)dyn;
    ushortT* Xh   = (ushortT*)(out1 + (size_t)g * KO * TVL);
    ushortT* Xl   = Xh + (size_t)g * TVL * 256;

    hipLaunchKernelGGL(ksplit_w1, dim3((KO * CIN + 255) / 256), dim3(256), 0, stream, cw, W1h, W1l, zb);
    hipLaunchKernelGGL(ksplit_w3, dim3((CO * KK3 + 255) / 256), dim3(256), 0, stream, tw, W3h, W3l);

    for (int n0 = 0; n0 < 16; n0 += g) {
        hipLaunchKernelGGL(ktrans_split, dim3(235, 8, g), dim3(256), 0, stream,
                           x + (size_t)n0 * CIN * TVL, (size_t)CIN * TVL, Xh, Xl);
        hipLaunchKernelGGL(k1_mfma, dim3(59, 6, g), dim3(256), 0, stream,
                           W1h, W1l, Xh, Xl, zb, cb, out1);
        hipLaunchKernelGGL(k2_sgc, dim3(g * 150), dim3(256), 0, stream,
                           out1, A, Mm, g1, b1, m1, v1, out1 /* h = k=0 plane */);
        hipLaunchKernelGGL(ktrans_split, dim3(235, 8, g), dim3(256), 0, stream,
                           out1, (size_t)KO * TVL, Xh, Xl);
        hipLaunchKernelGGL(k3_mfma, dim3(59, 2, g), dim3(256), 0, stream,
                           W3h, W3l, Xh, Xl, zb, tb, g2, b2, m2, v2, x, out, n0);
    }
}